// Round 2
// baseline (1934.256 us; speedup 1.0000x reference)
//
#include <hip/hip_runtime.h>
#include <stdint.h>

// Problem constants
#define B_ 8
#define N_ 4096
#define H_ 8
#define DH_ 64
#define DIM_ 512
#define M_ 266
#define MP_ 320          // padded feature dim (5 tiles of 64)
#define BH_ 64
#define BNROWS_ 32768
#define NSPLIT_ 2
#define CN_ 0.35355339059327373f      // 64^-0.25
#define RATIO_ 0.06131393394849658f   // 266^-0.5
#define EPS_ 1e-4f

typedef __bf16 bf16x8 __attribute__((ext_vector_type(8)));
typedef float f32x4 __attribute__((ext_vector_type(4)));

__device__ __forceinline__ uint32_t f2bf(float f) {
  uint32_t u = __float_as_uint(f);
  u += 0x7FFFu + ((u >> 16) & 1u);   // RNE
  return u >> 16;
}
__device__ __forceinline__ float bflo(uint32_t u) { return __uint_as_float(u << 16); }
__device__ __forceinline__ float bfhi(uint32_t u) { return __uint_as_float(u & 0xFFFF0000u); }
__device__ __forceinline__ void unp8(uint4 u, float* f) {
  f[0] = bflo(u.x); f[1] = bfhi(u.x); f[2] = bflo(u.y); f[3] = bfhi(u.y);
  f[4] = bflo(u.z); f[5] = bfhi(u.z); f[6] = bflo(u.w); f[7] = bfhi(u.w);
}
__device__ __forceinline__ float f4get(const float4& v, int i) {
  return ((const float*)&v)[i];
}
// monotonic float<->uint encode for atomicMax on signed floats
__device__ __forceinline__ uint32_t fenc(float f) {
  uint32_t u = __float_as_uint(f);
  return u ^ ((uint32_t)((int32_t)u >> 31) | 0x80000000u);
}
__device__ __forceinline__ float fdec(uint32_t e) {
  uint32_t u = (e & 0x80000000u) ? (e ^ 0x80000000u) : ~e;
  return __uint_as_float(u);
}

__global__ void init_stab(uint32_t* s) { *s = 0u; }

// w: [512][512] (k,n) row-major -> wt: [512][512] (n,k) bf16
__global__ __launch_bounds__(256) void cast_wt(const float* __restrict__ w,
                                               uint16_t* __restrict__ wt) {
  int i = blockIdx.x * 256 + threadIdx.x;   // 262144
  int k = i >> 9, n = i & 511;
  wt[(size_t)n * 512 + k] = (uint16_t)f2bf(w[i]);
}

// ---------------- bf16 MFMA GEMM: C[M,N] = A[M,K] * Bt[N,K]^T (+bias) ----------------
// 128x128 tile, BK=32, 256 thr (4 waves 2x2), double-buffered LDS.
// AF32: A operand is fp32 (converted to bf16 during staging). CBF16: C stored bf16.
#define GKP_ 40   // 32 + 8 pad

template <bool AF32, bool CBF16>
__global__ __launch_bounds__(256) void gemm_k(const void* __restrict__ Av,
                                              const uint16_t* __restrict__ Bt,
                                              void* __restrict__ Cv,
                                              const float* __restrict__ bias,
                                              int Ndim, int Kdim, int lda) {
  __shared__ uint16_t As[2][128 * GKP_];
  __shared__ uint16_t Bs[2][128 * GKP_];
  const int t = threadIdx.x;
  const int lane = t & 63;
  const int wave = t >> 6;
  const int wr = (wave >> 1) * 64, wc = (wave & 1) * 64;
  const int g = lane >> 4, r16 = lane & 15;
  const int srow = t >> 2;            // 0..63
  const int skk = (t & 3) * 8;        // 0,8,16,24
  const size_t rowA0 = (size_t)blockIdx.x * 128;
  const size_t rowB0 = (size_t)blockIdx.y * 128;

  f32x4 acc[4][4];
#pragma unroll
  for (int i = 0; i < 4; ++i)
#pragma unroll
    for (int j = 0; j < 4; ++j) acc[i][j] = (f32x4){0.f, 0.f, 0.f, 0.f};

  const int NK = Kdim >> 5;
  auto stage = [&](int kt, int buf) {
    uint4 a0, a1;
    if constexpr (AF32) {
      const float* ga = (const float*)Av + (rowA0 + srow) * (size_t)lda + kt * 32 + skk;
      float4 x0 = *(const float4*)ga;
      float4 x1 = *(const float4*)(ga + 4);
      float4 y0 = *(const float4*)(ga + 64 * (size_t)lda);
      float4 y1 = *(const float4*)(ga + 64 * (size_t)lda + 4);
      a0.x = f2bf(x0.x) | (f2bf(x0.y) << 16);
      a0.y = f2bf(x0.z) | (f2bf(x0.w) << 16);
      a0.z = f2bf(x1.x) | (f2bf(x1.y) << 16);
      a0.w = f2bf(x1.z) | (f2bf(x1.w) << 16);
      a1.x = f2bf(y0.x) | (f2bf(y0.y) << 16);
      a1.y = f2bf(y0.z) | (f2bf(y0.w) << 16);
      a1.z = f2bf(y1.x) | (f2bf(y1.y) << 16);
      a1.w = f2bf(y1.z) | (f2bf(y1.w) << 16);
    } else {
      const uint16_t* ga = (const uint16_t*)Av + (rowA0 + srow) * (size_t)lda + kt * 32 + skk;
      a0 = *(const uint4*)ga;
      a1 = *(const uint4*)(ga + 64 * (size_t)lda);
    }
    const uint16_t* gb = Bt + (rowB0 + srow) * (size_t)Kdim + kt * 32 + skk;
    uint4 b0 = *(const uint4*)gb;
    uint4 b1 = *(const uint4*)(gb + 64 * (size_t)Kdim);
    *(uint4*)&As[buf][srow * GKP_ + skk] = a0;
    *(uint4*)&As[buf][(srow + 64) * GKP_ + skk] = a1;
    *(uint4*)&Bs[buf][srow * GKP_ + skk] = b0;
    *(uint4*)&Bs[buf][(srow + 64) * GKP_ + skk] = b1;
  };
  stage(0, 0);
  for (int kt = 0; kt < NK; ++kt) {
    __syncthreads();
    if (kt + 1 < NK) stage(kt + 1, (kt + 1) & 1);
    const uint16_t* as = As[kt & 1];
    const uint16_t* bs = Bs[kt & 1];
    bf16x8 af[4], bfr[4];
#pragma unroll
    for (int i = 0; i < 4; ++i)
      af[i] = *(const bf16x8*)&as[(wr + i * 16 + r16) * GKP_ + g * 8];
#pragma unroll
    for (int j = 0; j < 4; ++j)
      bfr[j] = *(const bf16x8*)&bs[(wc + j * 16 + r16) * GKP_ + g * 8];
#pragma unroll
    for (int i = 0; i < 4; ++i)
#pragma unroll
      for (int j = 0; j < 4; ++j)
        acc[i][j] = __builtin_amdgcn_mfma_f32_16x16x32_bf16(af[i], bfr[j], acc[i][j], 0, 0, 0);
  }
  // epilogue: C row = (lane>>4)*4+reg, col = lane&15 (verified gfx950 layout)
#pragma unroll
  for (int i = 0; i < 4; ++i) {
    const size_t row0 = rowA0 + wr + i * 16 + g * 4;
#pragma unroll
    for (int j = 0; j < 4; ++j) {
      const size_t col = rowB0 + wc + j * 16 + r16;
      float badd = bias ? bias[col] : 0.f;
#pragma unroll
      for (int q = 0; q < 4; ++q) {
        float val = acc[i][j][q] + badd;
        if constexpr (CBF16)
          ((uint16_t*)Cv)[(row0 + q) * (size_t)Ndim + col] = (uint16_t)f2bf(val);
        else
          ((float*)Cv)[(row0 + q) * (size_t)Ndim + col] = val;
      }
    }
  }
}

// ---------------- stab_k: global max of cn*(k . proj_m) ----------------
__global__ __launch_bounds__(256) void stab_k_kernel(const uint16_t* __restrict__ kb,
                                                     const float* __restrict__ proj,
                                                     uint32_t* __restrict__ stab) {
  __shared__ float kt[64][68];   // [d][n]
  __shared__ float pt[64][68];   // [d][m]
  __shared__ float wred[4];
  const int t = threadIdx.x;
  const int bh = blockIdx.y, b = bh >> 3, h = bh & 7;
  const int n0 = blockIdx.x * 64;
#pragma unroll
  for (int i = 0; i < 2; ++i) {
    int lin = i * 256 + t;
    int row = lin >> 3, c8 = (lin & 7) * 8;
    uint4 u = *(const uint4*)&kb[((size_t)(b * N_ + n0 + row)) * DIM_ + h * DH_ + c8];
    float f[8]; unp8(u, f);
#pragma unroll
    for (int j = 0; j < 8; ++j) kt[c8 + j][row] = f[j];
  }
  const int ty = t >> 4, tx = t & 15;
  float vmax = -3.4e38f;
  for (int mt = 0; mt < 5; ++mt) {
    __syncthreads();
#pragma unroll
    for (int i = 0; i < 4; ++i) {
      int lin = i * 256 + t;
      int ml = lin >> 4, c4 = (lin & 15) * 4;
      int mg = mt * 64 + ml;
      float4 v = (mg < M_) ? *(const float4*)&proj[mg * DH_ + c4] : make_float4(0.f, 0.f, 0.f, 0.f);
      pt[c4 + 0][ml] = v.x; pt[c4 + 1][ml] = v.y; pt[c4 + 2][ml] = v.z; pt[c4 + 3][ml] = v.w;
    }
    __syncthreads();
    float s[4][4] = {};
    for (int d = 0; d < 64; ++d) {
      float4 pm = *(const float4*)&pt[d][ty * 4];
      float4 kn = *(const float4*)&kt[d][tx * 4];
#pragma unroll
      for (int i = 0; i < 4; ++i)
#pragma unroll
        for (int j = 0; j < 4; ++j) s[i][j] += f4get(pm, i) * f4get(kn, j);
    }
    int mbase = mt * 64 + ty * 4;
#pragma unroll
    for (int i = 0; i < 4; ++i)
      if (mbase + i < M_)
#pragma unroll
        for (int j = 0; j < 4; ++j) vmax = fmaxf(vmax, s[i][j]);
  }
#pragma unroll
  for (int off = 32; off; off >>= 1) vmax = fmaxf(vmax, __shfl_xor(vmax, off));
  if ((t & 63) == 0) wred[t >> 6] = vmax;
  __syncthreads();
  if (t == 0) {
    float m = fmaxf(fmaxf(wred[0], wred[1]), fmaxf(wred[2], wred[3]));
    atomicMax(stab, fenc(CN_ * m));
  }
}

// ---------------- context partials + k_cumsum partials ----------------
// grid: (mt=5, bh=64, ns=2); block owns 64 m x 64 e, loops 2048 n in tiles of 32
__global__ __launch_bounds__(256) void ctx_kernel(const uint16_t* __restrict__ kb,
                                                  const uint16_t* __restrict__ vb,
                                                  const float* __restrict__ proj,
                                                  const uint32_t* __restrict__ stab_e,
                                                  float* __restrict__ ctxp,
                                                  float* __restrict__ kcump) {
  __shared__ float pt[64][68];      // [d][m]
  __shared__ float ktile[64][36];   // [d][n]
  __shared__ float vtile[32][68];   // [n][e]
  __shared__ float sbuf[32][68];    // [n][m] kp values
  __shared__ float dk[32];
  __shared__ float kcred[64][9];
  const int t = threadIdx.x;
  const int mt = blockIdx.x;
  const int bh = blockIdx.y, b = bh >> 3, h = bh & 7;
  const int ns = blockIdx.z;
  const float stab = fdec(*stab_e);
#pragma unroll
  for (int i = 0; i < 4; ++i) {   // stage proj tile once (zero-padded)
    int lin = i * 256 + t;
    int ml = lin >> 4, c4 = (lin & 15) * 4;
    int mg = mt * 64 + ml;
    float4 v = (mg < M_) ? *(const float4*)&proj[mg * DH_ + c4] : make_float4(0.f, 0.f, 0.f, 0.f);
    pt[c4 + 0][ml] = v.x; pt[c4 + 1][ml] = v.y; pt[c4 + 2][ml] = v.z; pt[c4 + 3][ml] = v.w;
  }
  const int sy = t >> 3, sx = t & 7;     // S phase: 2m x 4n
  const int cy = t >> 4, cx = t & 15;    // accum phase: 4m x 4e
  float cacc[4][4] = {};
  float kc[2] = {0.f, 0.f};

  for (int nt = 0; nt < 64; ++nt) {
    const int n0 = ns * 2048 + nt * 32;
    __syncthreads();
    {
      int row = t >> 3, c8 = (t & 7) * 8;
      size_t base = ((size_t)(b * N_ + n0 + row)) * DIM_ + h * DH_ + c8;
      uint4 uk = *(const uint4*)&kb[base];
      uint4 uv = *(const uint4*)&vb[base];
      float fk[8], fv[8]; unp8(uk, fk); unp8(uv, fv);
#pragma unroll
      for (int j = 0; j < 8; ++j) ktile[c8 + j][row] = fk[j];
      *(float4*)&vtile[row][c8 + 0] = make_float4(fv[0], fv[1], fv[2], fv[3]);
      *(float4*)&vtile[row][c8 + 4] = make_float4(fv[4], fv[5], fv[6], fv[7]);
    }
    __syncthreads();
    if (t < 32) {
      float sd = 0.f;
      for (int d = 0; d < 64; ++d) { float kv = ktile[d][t]; sd += kv * kv; }
      dk[t] = 0.5f * CN_ * CN_ * sd;
    }
    __syncthreads();
    float s[2][4] = {};
    for (int d = 0; d < 64; ++d) {
      float2 pm = *(const float2*)&pt[d][sy * 2];
      float4 kn = *(const float4*)&ktile[d][sx * 4];
      s[0][0] += pm.x * f4get(kn, 0); s[0][1] += pm.x * f4get(kn, 1);
      s[0][2] += pm.x * f4get(kn, 2); s[0][3] += pm.x * f4get(kn, 3);
      s[1][0] += pm.y * f4get(kn, 0); s[1][1] += pm.y * f4get(kn, 1);
      s[1][2] += pm.y * f4get(kn, 2); s[1][3] += pm.y * f4get(kn, 3);
    }
#pragma unroll
    for (int i = 0; i < 2; ++i) {
      int mg = mt * 64 + sy * 2 + i;
#pragma unroll
      for (int j = 0; j < 4; ++j) {
        float kp = 0.f;
        if (mg < M_) kp = RATIO_ * (__expf(CN_ * s[i][j] - dk[sx * 4 + j] - stab) + EPS_);
        sbuf[sx * 4 + j][sy * 2 + i] = kp;
        kc[i] += kp;
      }
    }
    __syncthreads();
    for (int nl = 0; nl < 32; ++nl) {
      float4 kpv = *(const float4*)&sbuf[nl][cy * 4];
      float4 vv = *(const float4*)&vtile[nl][cx * 4];
#pragma unroll
      for (int i = 0; i < 4; ++i)
#pragma unroll
        for (int j = 0; j < 4; ++j) cacc[i][j] += f4get(kpv, i) * f4get(vv, j);
    }
  }
  const size_t ctxbase = ((size_t)(ns * BH_ + bh) * MP_ + mt * 64) * DH_;
#pragma unroll
  for (int i = 0; i < 4; ++i) {
    float4 o = make_float4(cacc[i][0], cacc[i][1], cacc[i][2], cacc[i][3]);
    *(float4*)&ctxp[ctxbase + (size_t)(cy * 4 + i) * DH_ + cx * 4] = o;
  }
  kcred[sy * 2 + 0][sx] = kc[0];
  kcred[sy * 2 + 1][sx] = kc[1];
  __syncthreads();
  if (t < 64) {
    float s8 = 0.f;
#pragma unroll
    for (int j = 0; j < 8; ++j) s8 += kcred[t][j];
    kcump[(size_t)(ns * BH_ + bh) * MP_ + mt * 64 + t] = s8;
  }
}

__global__ __launch_bounds__(256) void merge_kernel(const float* __restrict__ ctxp,
                                                    const float* __restrict__ kcump,
                                                    float* __restrict__ ctxg,
                                                    float* __restrict__ kcumg) {
  int idx = blockIdx.x * 256 + threadIdx.x;
  const int total = BH_ * MP_ * DH_;
  if (idx < total) {
    float s = 0.f;
#pragma unroll
    for (int p = 0; p < NSPLIT_; ++p) s += ctxp[(size_t)p * total + idx];
    ctxg[idx] = s;
  }
  const int ktotal = BH_ * MP_;
  if (idx < ktotal) {
    float s = 0.f;
#pragma unroll
    for (int p = 0; p < NSPLIT_; ++p) s += kcump[(size_t)p * ktotal + idx];
    kcumg[idx] = s;
  }
}

// ---------------- attention output: qp row-softmax-feature + qp@context ----------------
// grid: (nt=128 of 32 q-rows, bh=64)
__global__ __launch_bounds__(256) void attn_out_kernel(const uint16_t* __restrict__ qb,
                                                       const float* __restrict__ proj,
                                                       const float* __restrict__ ctx,
                                                       const float* __restrict__ kcum,
                                                       uint16_t* __restrict__ attnb) {
  __shared__ __align__(16) char smem[54272];
  float (*qt)[36] = (float (*)[36])(smem);                 // [d][n]  pass1
  float (*pt)[68] = (float (*)[68])(smem + 9216);          // [d][m]  pass1
  float (*ctile)[68] = (float (*)[68])(smem);              // [m][e]  pass2 (overlay)
  _Float16 (*qph)[34] = (_Float16 (*)[34])(smem + 26624);  // [320][n] raw qdash then qp
  float* dqv = (float*)(smem + 48384);
  float* offv = (float*)(smem + 48512);
  float (*rmred)[33] = (float (*)[33])(smem + 48640);
  float (*denred)[9] = (float (*)[9])(smem + 52864);
  float* dinv = (float*)(smem + 54016);

  const int t = threadIdx.x;
  const int bh = blockIdx.y, b = bh >> 3, h = bh & 7;
  const int n0 = blockIdx.x * 32;
  {
    int row = t >> 3, c8 = (t & 7) * 8;
    uint4 u = *(const uint4*)&qb[((size_t)(b * N_ + n0 + row)) * DIM_ + h * DH_ + c8];
    float f[8]; unp8(u, f);
#pragma unroll
    for (int j = 0; j < 8; ++j) qt[c8 + j][row] = f[j];
  }
  __syncthreads();
  if (t < 32) {
    float sd = 0.f;
    for (int d = 0; d < 64; ++d) { float q = qt[d][t]; sd += q * q; }
    dqv[t] = 0.5f * CN_ * CN_ * sd;
  }
  const int sy = t >> 3, sx = t & 7;
  float pmax[4] = {-3.4e38f, -3.4e38f, -3.4e38f, -3.4e38f};
  for (int mt = 0; mt < 5; ++mt) {
    __syncthreads();
#pragma unroll
    for (int i = 0; i < 4; ++i) {
      int lin = i * 256 + t;
      int ml = lin >> 4, c4 = (lin & 15) * 4;
      int mg = mt * 64 + ml;
      float4 v = (mg < M_) ? *(const float4*)&proj[mg * DH_ + c4] : make_float4(0.f, 0.f, 0.f, 0.f);
      pt[c4 + 0][ml] = v.x; pt[c4 + 1][ml] = v.y; pt[c4 + 2][ml] = v.z; pt[c4 + 3][ml] = v.w;
    }
    __syncthreads();
    float s[2][4] = {};
    for (int d = 0; d < 64; ++d) {
      float2 pm = *(const float2*)&pt[d][sy * 2];
      float4 qn = *(const float4*)&qt[d][sx * 4];
      s[0][0] += pm.x * f4get(qn, 0); s[0][1] += pm.x * f4get(qn, 1);
      s[0][2] += pm.x * f4get(qn, 2); s[0][3] += pm.x * f4get(qn, 3);
      s[1][0] += pm.y * f4get(qn, 0); s[1][1] += pm.y * f4get(qn, 1);
      s[1][2] += pm.y * f4get(qn, 2); s[1][3] += pm.y * f4get(qn, 3);
    }
#pragma unroll
    for (int i = 0; i < 2; ++i) {
      int mg = mt * 64 + sy * 2 + i;
#pragma unroll
      for (int j = 0; j < 4; ++j) {
        float qd = CN_ * s[i][j];
        qph[mg][sx * 4 + j] = (_Float16)qd;
        if (mg < M_) pmax[j] = fmaxf(pmax[j], qd);
      }
    }
  }
#pragma unroll
  for (int j = 0; j < 4; ++j) rmred[sx * 4 + j][sy] = pmax[j];
  __syncthreads();
  if (t < 32) {
    float mval = -3.4e38f;
    for (int y = 0; y < 32; ++y) mval = fmaxf(mval, rmred[t][y]);
    offv[t] = mval + dqv[t];
  }
  __syncthreads();
  for (int idx = t; idx < MP_ * 32; idx += 256) {   // qdash -> qp in place
    int m = idx >> 5, n = idx & 31;
    float raw = (float)qph[m][n];
    float qp = RATIO_ * (__expf(raw - offv[n]) + EPS_);
    qph[m][n] = (_Float16)qp;
  }
  __syncthreads();
  {
    int n = t & 31, ch = t >> 5;
    float sden = 0.f;
    for (int mm = ch * 40; mm < ch * 40 + 40; ++mm)
      sden += (float)qph[mm][n] * kcum[(size_t)bh * MP_ + mm];
    denred[n][ch] = sden;
  }
  __syncthreads();
  if (t < 32) {
    float sden = 0.f;
#pragma unroll
    for (int ch = 0; ch < 8; ++ch) sden += denred[t][ch];
    dinv[t] = 1.0f / sden;
  }
  // pass 2: out[n][e] = sum_m qp * ctx
  const int dy = t >> 4, dx = t & 15;   // 2n x 4e
  float oacc[2][4] = {};
  for (int mt = 0; mt < 5; ++mt) {
    __syncthreads();
#pragma unroll
    for (int i = 0; i < 4; ++i) {
      int lin = i * 256 + t;
      int ml = lin >> 4, c4 = (lin & 15) * 4;
      *(float4*)&ctile[ml][c4] =
          *(const float4*)&ctx[((size_t)bh * MP_ + mt * 64 + ml) * DH_ + c4];
    }
    __syncthreads();
    for (int ml = 0; ml < 64; ++ml) {
      float q0 = (float)qph[mt * 64 + ml][dy * 2 + 0];
      float q1 = (float)qph[mt * 64 + ml][dy * 2 + 1];
      float4 cv = *(const float4*)&ctile[ml][dx * 4];
#pragma unroll
      for (int j = 0; j < 4; ++j) {
        oacc[0][j] += q0 * f4get(cv, j);
        oacc[1][j] += q1 * f4get(cv, j);
      }
    }
  }
#pragma unroll
  for (int i = 0; i < 2; ++i) {
    int nl = dy * 2 + i;
    float di = dinv[nl];
    size_t obase = (size_t)(b * N_ + n0 + nl) * DIM_ + h * DH_ + dx * 4;
    uint2 o;
    o.x = f2bf(oacc[i][0] * di) | (f2bf(oacc[i][1] * di) << 16);
    o.y = f2bf(oacc[i][2] * di) | (f2bf(oacc[i][3] * di) << 16);
    *(uint2*)&attnb[obase] = o;
  }
}

extern "C" void kernel_launch(void* const* d_in, const int* in_sizes, int n_in,
                              void* d_out, int out_size, void* d_ws, size_t ws_size,
                              hipStream_t stream) {
  const float* x = (const float*)d_in[0];
  const float* Wq = (const float*)d_in[1];
  const float* Wk = (const float*)d_in[2];
  const float* Wv = (const float*)d_in[3];
  const float* Wo = (const float*)d_in[4];
  const float* bo = (const float*)d_in[5];
  const float* proj = (const float*)d_in[6];
  float* out = (float*)d_out;

  char* ws = (char*)d_ws;
  size_t off = 0;
  auto alloc = [&](size_t bytes) {
    char* p = ws + off;
    off += (bytes + 255) & ~(size_t)255;
    return p;
  };
  // ws total ~51.6 MB
  uint16_t* wqT = (uint16_t*)alloc((size_t)512 * 512 * 2);
  uint16_t* wkT = (uint16_t*)alloc((size_t)512 * 512 * 2);
  uint16_t* wvT = (uint16_t*)alloc((size_t)512 * 512 * 2);
  uint16_t* woT = (uint16_t*)alloc((size_t)512 * 512 * 2);
  uint16_t* vb = (uint16_t*)alloc((size_t)BNROWS_ * DIM_ * 2);   // v, later attn out
  float* ctxg = (float*)alloc((size_t)BH_ * MP_ * DH_ * 4);
  float* kcumg = (float*)alloc((size_t)BH_ * MP_ * 4);
  float* ctxp = (float*)alloc((size_t)NSPLIT_ * BH_ * MP_ * DH_ * 4);
  float* kcump = (float*)alloc((size_t)NSPLIT_ * BH_ * MP_ * 4);
  uint32_t* stab = (uint32_t*)alloc(256);
  // q,k staged in d_out (fully overwritten by the final GEMM afterwards)
  uint16_t* qb = (uint16_t*)d_out;
  uint16_t* kb = qb + (size_t)BNROWS_ * DIM_;
  uint16_t* attnb = vb;

  init_stab<<<1, 1, 0, stream>>>(stab);
  cast_wt<<<1024, 256, 0, stream>>>(Wq, wqT);
  cast_wt<<<1024, 256, 0, stream>>>(Wk, wkT);
  cast_wt<<<1024, 256, 0, stream>>>(Wv, wvT);
  cast_wt<<<1024, 256, 0, stream>>>(Wo, woT);

  dim3 gg(256, 4);
  gemm_k<true, true><<<gg, 256, 0, stream>>>(x, wqT, qb, nullptr, 512, 512, 512);
  gemm_k<true, true><<<gg, 256, 0, stream>>>(x, wkT, kb, nullptr, 512, 512, 512);
  gemm_k<true, true><<<gg, 256, 0, stream>>>(x, wvT, vb, nullptr, 512, 512, 512);

  stab_k_kernel<<<dim3(64, 64), 256, 0, stream>>>(kb, proj, stab);
  ctx_kernel<<<dim3(5, 64, 2), 256, 0, stream>>>(kb, vb, proj, stab, ctxp, kcump);
  merge_kernel<<<5120, 256, 0, stream>>>(ctxp, kcump, ctxg, kcumg);
  attn_out_kernel<<<dim3(128, 64), 256, 0, stream>>>(qb, proj, ctxg, kcumg, attnb);
  gemm_k<false, false><<<gg, 256, 0, stream>>>(attnb, woT, out, bo, 512, 512, 512);
}

// Round 4
// 353.694 us; speedup vs baseline: 5.4687x; 5.4687x over previous
//
#include <hip/hip_runtime.h>
#include <stdint.h>

// Problem constants
#define B_ 8
#define N_ 4096
#define H_ 8
#define DH_ 64
#define DIM_ 512
#define M_ 266
#define MP_ 320          // padded feature dim
#define BH_ 64
#define BNROWS_ 32768
#define NSPLIT_ 2
#define CN_ 0.35355339059327373f      // 64^-0.25
#define RATIO_ 0.06131393394849658f   // 266^-0.5
#define EPS_ 1e-4f
#define REPS_ (RATIO_ * EPS_)

typedef __bf16 bf16x8 __attribute__((ext_vector_type(8)));
typedef float f32x4 __attribute__((ext_vector_type(4)));

union U8 { bf16x8 v; uint4 u; uint2 u2[2]; uint16_t s[8]; };

__device__ __forceinline__ uint32_t f2bf(float f) {
  uint32_t u = __float_as_uint(f);
  u += 0x7FFFu + ((u >> 16) & 1u);   // RNE
  return u >> 16;
}
__device__ __forceinline__ uint32_t pkbf(float a, float b) {
  uint32_t r;
  asm("v_cvt_pk_bf16_f32 %0, %1, %2" : "=v"(r) : "v"(a), "v"(b));
  return r;
}
__device__ __forceinline__ float bflo(uint32_t u) { return __uint_as_float(u << 16); }
__device__ __forceinline__ float bfhi(uint32_t u) { return __uint_as_float(u & 0xFFFF0000u); }
__device__ __forceinline__ void unp8(uint4 u, float* f) {
  f[0] = bflo(u.x); f[1] = bfhi(u.x); f[2] = bflo(u.y); f[3] = bfhi(u.y);
  f[4] = bflo(u.z); f[5] = bfhi(u.z); f[6] = bflo(u.w); f[7] = bfhi(u.w);
}
__device__ __forceinline__ float f4get(const float4& v, int i) {
  return ((const float*)&v)[i];
}
// monotonic float<->uint encode for atomicMax on signed floats
__device__ __forceinline__ uint32_t fenc(float f) {
  uint32_t u = __float_as_uint(f);
  return u ^ ((uint32_t)((int32_t)u >> 31) | 0x80000000u);
}
__device__ __forceinline__ float fdec(uint32_t e) {
  uint32_t u = (e & 0x80000000u) ? (e ^ 0x80000000u) : ~e;
  return __uint_as_float(u);
}
// position-permutation: proj row stored at position p holds original row pi(p)
__device__ __forceinline__ int piperm(int p) {
  int tmt = p >> 4, r = p & 15;
  return 32 * (tmt >> 1) + 8 * (r >> 2) + 4 * (tmt & 1) + (r & 3);
}
// slot permutation: attn A-frag slot kappa (within a 32-window) holds position
// phi(kappa) = (i<4 ? 4g+i : 16+4g+(i-4)), kappa=8g+i. phinv is its inverse:
// ctx stored at slot phinv(p&31) so linear B-side reads pair with A-side slots.
__device__ __forceinline__ int phinv(int r) {  // r in [0,32)
  int lo = r & 15;
  return 8 * (lo >> 2) + (lo & 3) + ((r >> 4) << 2);
}

__global__ void init_stab(uint32_t* s) { *s = fenc(-3.4e38f); }

// w: [512][512] (k,n) row-major -> wt: [512][512] (n,k) bf16
__global__ __launch_bounds__(256) void cast_wt(const float* __restrict__ w,
                                               uint16_t* __restrict__ wt) {
  int i = blockIdx.x * 256 + threadIdx.x;
  int k = i >> 9, n = i & 511;
  wt[(size_t)n * 512 + k] = (uint16_t)f2bf(w[i]);
}

// proj fp32 [266][64] -> projb bf16 [320][64], permuted rows, zero-padded
__global__ __launch_bounds__(256) void cast_projb(const float* __restrict__ proj,
                                                  uint16_t* __restrict__ projb) {
  int i = blockIdx.x * 256 + threadIdx.x;   // 320*64 = 20480
  if (i >= MP_ * DH_) return;
  int p = i >> 6, d = i & 63;
  int pi = piperm(p);
  float v = (pi < M_) ? proj[pi * DH_ + d] : 0.f;
  projb[i] = (uint16_t)f2bf(v);
}

// ---------------- bf16 MFMA GEMM: C[M,N] = A[M,K] * Bt[N,K]^T (+bias) ----------------
#define GKP_ 40

template <bool AF32, bool CBF16, bool VT>
__global__ __launch_bounds__(256) void gemm_k(const void* __restrict__ Av,
                                              const uint16_t* __restrict__ Bt,
                                              void* __restrict__ Cv,
                                              const float* __restrict__ bias,
                                              int Ndim, int Kdim, int lda) {
  __shared__ uint16_t As[2][128 * GKP_];
  __shared__ uint16_t Bs[2][128 * GKP_];
  const int t = threadIdx.x;
  const int lane = t & 63;
  const int wave = t >> 6;
  const int wr = (wave >> 1) * 64, wc = (wave & 1) * 64;
  const int g = lane >> 4, r16 = lane & 15;
  const int srow = t >> 2;
  const int skk = (t & 3) * 8;
  const size_t rowA0 = (size_t)blockIdx.x * 128;
  const size_t rowB0 = (size_t)blockIdx.y * 128;

  f32x4 acc[4][4];
#pragma unroll
  for (int i = 0; i < 4; ++i)
#pragma unroll
    for (int j = 0; j < 4; ++j) acc[i][j] = (f32x4){0.f, 0.f, 0.f, 0.f};

  const int NK = Kdim >> 5;
  auto stage = [&](int kt, int buf) {
    uint4 a0, a1;
    if constexpr (AF32) {
      const float* ga = (const float*)Av + (rowA0 + srow) * (size_t)lda + kt * 32 + skk;
      float4 x0 = *(const float4*)ga;
      float4 x1 = *(const float4*)(ga + 4);
      float4 y0 = *(const float4*)(ga + 64 * (size_t)lda);
      float4 y1 = *(const float4*)(ga + 64 * (size_t)lda + 4);
      a0.x = f2bf(x0.x) | (f2bf(x0.y) << 16);
      a0.y = f2bf(x0.z) | (f2bf(x0.w) << 16);
      a0.z = f2bf(x1.x) | (f2bf(x1.y) << 16);
      a0.w = f2bf(x1.z) | (f2bf(x1.w) << 16);
      a1.x = f2bf(y0.x) | (f2bf(y0.y) << 16);
      a1.y = f2bf(y0.z) | (f2bf(y0.w) << 16);
      a1.z = f2bf(y1.x) | (f2bf(y1.y) << 16);
      a1.w = f2bf(y1.z) | (f2bf(y1.w) << 16);
    } else {
      const uint16_t* ga = (const uint16_t*)Av + (rowA0 + srow) * (size_t)lda + kt * 32 + skk;
      a0 = *(const uint4*)ga;
      a1 = *(const uint4*)(ga + 64 * (size_t)lda);
    }
    const uint16_t* gb = Bt + (rowB0 + srow) * (size_t)Kdim + kt * 32 + skk;
    uint4 b0 = *(const uint4*)gb;
    uint4 b1 = *(const uint4*)(gb + 64 * (size_t)Kdim);
    *(uint4*)&As[buf][srow * GKP_ + skk] = a0;
    *(uint4*)&As[buf][(srow + 64) * GKP_ + skk] = a1;
    *(uint4*)&Bs[buf][srow * GKP_ + skk] = b0;
    *(uint4*)&Bs[buf][(srow + 64) * GKP_ + skk] = b1;
  };
  stage(0, 0);
  for (int kt = 0; kt < NK; ++kt) {
    __syncthreads();
    if (kt + 1 < NK) stage(kt + 1, (kt + 1) & 1);
    const uint16_t* as = As[kt & 1];
    const uint16_t* bs = Bs[kt & 1];
    bf16x8 af[4], bfr[4];
#pragma unroll
    for (int i = 0; i < 4; ++i)
      af[i] = *(const bf16x8*)&as[(wr + i * 16 + r16) * GKP_ + g * 8];
#pragma unroll
    for (int j = 0; j < 4; ++j)
      bfr[j] = *(const bf16x8*)&bs[(wc + j * 16 + r16) * GKP_ + g * 8];
#pragma unroll
    for (int i = 0; i < 4; ++i)
#pragma unroll
      for (int j = 0; j < 4; ++j)
        acc[i][j] = __builtin_amdgcn_mfma_f32_16x16x32_bf16(af[i], bfr[j], acc[i][j], 0, 0, 0);
  }
  // epilogue: C row = (lane>>4)*4+reg, col = lane&15
#pragma unroll
  for (int i = 0; i < 4; ++i) {
    const size_t row0 = rowA0 + wr + i * 16 + g * 4;
#pragma unroll
    for (int j = 0; j < 4; ++j) {
      const size_t col = rowB0 + wc + j * 16 + r16;
      if constexpr (VT) {
        // C -> vT bf16 [bh][e][4096]; lane's 4 values are consecutive n
        int bb = (int)(row0 >> 12), n = (int)(row0 & 4095);
        int hh = (int)(col >> 6), e = (int)(col & 63);
        uint2 o;
        o.x = pkbf(acc[i][j][0], acc[i][j][1]);
        o.y = pkbf(acc[i][j][2], acc[i][j][3]);
        *(uint2*)&((uint16_t*)Cv)[((size_t)((bb * 8 + hh) * 64 + e)) * 4096 + n] = o;
      } else {
        float badd = bias ? bias[col] : 0.f;
#pragma unroll
        for (int q = 0; q < 4; ++q) {
          float val = acc[i][j][q] + badd;
          if constexpr (CBF16)
            ((uint16_t*)Cv)[(row0 + q) * (size_t)Ndim + col] = (uint16_t)f2bf(val);
          else
            ((float*)Cv)[(row0 + q) * (size_t)Ndim + col] = val;
        }
      }
    }
  }
}

// ---------------- stab: global max of CN*(k . proj) via MFMA ----------------
// grid (mt=5, bh=64, ns=4), 256 thr; wave w owns positions m16 = mt*64+w*16
__global__ __launch_bounds__(256) void stab_mfma(const uint16_t* __restrict__ kb,
                                                 const uint16_t* __restrict__ projb,
                                                 uint32_t* __restrict__ stab) {
  __shared__ uint16_t kt[2][32][72];
  __shared__ float wred[4];
  const int t = threadIdx.x, lane = t & 63, w = t >> 6;
  const int g = lane >> 4, r16 = lane & 15;
  const int mt = blockIdx.x, bh = blockIdx.y, ns = blockIdx.z;
  const int b = bh >> 3, h = bh & 7;
  const int m16 = mt * 64 + w * 16;
  const bool mvalid = piperm(m16 + r16) < M_;
  bf16x8 pj0 = *(const bf16x8*)&projb[(m16 + r16) * 64 + g * 8];
  bf16x8 pj1 = *(const bf16x8*)&projb[(m16 + r16) * 64 + 32 + g * 8];

  auto stage = [&](int it, int buf) {
    int n0 = ns * 1024 + it * 32;
    int row = t >> 3, c8 = t & 7;
    uint4 kv = *(const uint4*)&kb[((size_t)(b * N_ + n0 + row)) * DIM_ + h * DH_ + c8 * 8];
    *(uint4*)&kt[buf][row][c8 * 8] = kv;
  };
  stage(0, 0);
  __syncthreads();
  float vmax = -3.4e38f;
  for (int it = 0; it < 32; ++it) {
    int cur = it & 1;
    if (it + 1 < 32) stage(it + 1, cur ^ 1);
#pragma unroll
    for (int nsub = 0; nsub < 2; ++nsub) {
      bf16x8 ka0 = *(const bf16x8*)&kt[cur][nsub * 16 + r16][g * 8];
      bf16x8 ka1 = *(const bf16x8*)&kt[cur][nsub * 16 + r16][32 + g * 8];
      f32x4 c4 = (f32x4){0.f, 0.f, 0.f, 0.f};
      c4 = __builtin_amdgcn_mfma_f32_16x16x32_bf16(ka0, pj0, c4, 0, 0, 0);
      c4 = __builtin_amdgcn_mfma_f32_16x16x32_bf16(ka1, pj1, c4, 0, 0, 0);
      if (mvalid) {
        vmax = fmaxf(vmax, fmaxf(fmaxf(c4[0], c4[1]), fmaxf(c4[2], c4[3])));
      }
    }
    __syncthreads();
  }
#pragma unroll
  for (int off = 32; off; off >>= 1) vmax = fmaxf(vmax, __shfl_xor(vmax, off));
  if (lane == 0) wred[w] = vmax;
  __syncthreads();
  if (t == 0) {
    float m = fmaxf(fmaxf(wred[0], wred[1]), fmaxf(wred[2], wred[3]));
    atomicMax(stab, fenc(CN_ * m));
  }
}

// ---------------- ctx: flash-style kp-feature + kp^T @ v, MFMA ----------------
// grid (mt=5, bh=64, ns=2), 256 thr (4 waves); wave w owns m-positions [m16, m16+16)
__global__ __launch_bounds__(256) void ctx_mfma(const uint16_t* __restrict__ kb,
                                                const uint16_t* __restrict__ vTb,
                                                const uint16_t* __restrict__ projb,
                                                const uint32_t* __restrict__ stab_e,
                                                float* __restrict__ ctxp,
                                                float* __restrict__ kcump) {
  __shared__ uint16_t kt[2][32][72];
  __shared__ uint16_t vt[2][64][40];
  __shared__ float dk2[2][32];
  __shared__ uint16_t kpb[4][16][40];
  const int t = threadIdx.x, lane = t & 63, w = t >> 6;
  const int g = lane >> 4, r16 = lane & 15;
  const int mt = blockIdx.x, bh = blockIdx.y, ns = blockIdx.z;
  const int b = bh >> 3, h = bh & 7;
  const int m16 = mt * 64 + w * 16;
  const float stab = fdec(*stab_e);
  const bool mvalid = piperm(m16 + r16) < M_;
  bf16x8 pj0 = *(const bf16x8*)&projb[(m16 + r16) * 64 + g * 8];
  bf16x8 pj1 = *(const bf16x8*)&projb[(m16 + r16) * 64 + 32 + g * 8];

  auto stage = [&](int it, int buf) {
    int n0 = ns * 2048 + it * 32;
    {
      int row = t >> 3, c8 = t & 7;
      uint4 kv = *(const uint4*)&kb[((size_t)(b * N_ + n0 + row)) * DIM_ + h * DH_ + c8 * 8];
      *(uint4*)&kt[buf][row][c8 * 8] = kv;
      float f[8]; unp8(kv, f);
      float sq = f[0]*f[0]+f[1]*f[1]+f[2]*f[2]+f[3]*f[3]+f[4]*f[4]+f[5]*f[5]+f[6]*f[6]+f[7]*f[7];
      sq += __shfl_xor(sq, 1); sq += __shfl_xor(sq, 2); sq += __shfl_xor(sq, 4);
      if (c8 == 0) dk2[buf][row] = 0.5f * CN_ * CN_ * sq;
    }
    {
      int e = t >> 2, c = t & 3;
      uint4 vv = *(const uint4*)&vTb[((size_t)(bh * 64 + e)) * 4096 + n0 + c * 8];
      *(uint4*)&vt[buf][e][c * 8] = vv;
    }
  };
  f32x4 acc[4];
#pragma unroll
  for (int j = 0; j < 4; ++j) acc[j] = (f32x4){0.f, 0.f, 0.f, 0.f};
  float kcacc = 0.f;

  stage(0, 0);
  __syncthreads();
  for (int it = 0; it < 64; ++it) {
    int cur = it & 1;
    if (it + 1 < 64) stage(it + 1, cur ^ 1);
    // S phase (swapped): C col = m (r16), row = n-local (4g+q)
#pragma unroll
    for (int nsub = 0; nsub < 2; ++nsub) {
      bf16x8 ka0 = *(const bf16x8*)&kt[cur][nsub * 16 + r16][g * 8];
      bf16x8 ka1 = *(const bf16x8*)&kt[cur][nsub * 16 + r16][32 + g * 8];
      f32x4 c4 = (f32x4){0.f, 0.f, 0.f, 0.f};
      c4 = __builtin_amdgcn_mfma_f32_16x16x32_bf16(ka0, pj0, c4, 0, 0, 0);
      c4 = __builtin_amdgcn_mfma_f32_16x16x32_bf16(ka1, pj1, c4, 0, 0, 0);
      float4 dkv = *(const float4*)&dk2[cur][nsub * 16 + 4 * g];
      float kp[4];
#pragma unroll
      for (int q = 0; q < 4; ++q) {
        float arg = CN_ * c4[q] - f4get(dkv, q) - stab;
        float e = RATIO_ * __expf(arg) + REPS_;
        kp[q] = mvalid ? e : 0.f;
        kcacc += kp[q];
      }
      *(uint2*)&kpb[w][r16][nsub * 16 + 4 * g] = make_uint2(pkbf(kp[0], kp[1]), pkbf(kp[2], kp[3]));
    }
    // PV: A = kp[m-local][n32] (wave-local LDS), B = vT[e][n32]
    U8 kq; kq.u = *(const uint4*)&kpb[w][r16][g * 8];
#pragma unroll
    for (int j = 0; j < 4; ++j) {
      U8 vf; vf.u = *(const uint4*)&vt[cur][j * 16 + r16][g * 8];
      acc[j] = __builtin_amdgcn_mfma_f32_16x16x32_bf16(kq.v, vf.v, acc[j], 0, 0, 0);
    }
    __syncthreads();
  }
  // write ctx^T partials: lane holds ctx[m16+4g+q][e=j*16+r16]
#pragma unroll
  for (int j = 0; j < 4; ++j) {
    float4 o = make_float4(acc[j][0], acc[j][1], acc[j][2], acc[j][3]);
    *(float4*)&ctxp[(((size_t)ns * BH_ + bh) * 64 + j * 16 + r16) * MP_ + m16 + 4 * g] = o;
  }
  kcacc += __shfl_xor(kcacc, 16);
  kcacc += __shfl_xor(kcacc, 32);
  if (lane < 16) kcump[((size_t)ns * BH_ + bh) * MP_ + m16 + lane] = kcacc;
}

// merge partials: ctx -> bf16 [bh][e][320] in SLOT order (phinv), kcum -> fp32 [bh][320]
__global__ __launch_bounds__(256) void merge_kernel(const float* __restrict__ ctxp,
                                                    const float* __restrict__ kcump,
                                                    uint16_t* __restrict__ ctxgb,
                                                    float* __restrict__ kcumg) {
  int idx = blockIdx.x * 256 + threadIdx.x;
  const int total = BH_ * 64 * MP_;
  if (idx < total) {
    float s = 0.f;
#pragma unroll
    for (int p = 0; p < NSPLIT_; ++p) s += ctxp[(size_t)p * total + idx];
    int row = idx / MP_;
    int pos = idx - row * MP_;
    int col = (pos & ~31) + phinv(pos & 31);   // slot order for attn A-frag pairing
    ctxgb[(size_t)row * MP_ + col] = (uint16_t)f2bf(s);
  }
  const int ktotal = BH_ * MP_;
  if (idx < ktotal) {
    float s = 0.f;
#pragma unroll
    for (int p = 0; p < NSPLIT_; ++p) s += kcump[(size_t)p * ktotal + idx];
    kcumg[idx] = s;
  }
}

// ---------------- attention output: qp feature + qp @ ctx, MFMA ----------------
// grid (nchunk=8, bh=64), 512 thr (8 waves); wave w owns 16 q-rows per 128-row iter
__global__ __launch_bounds__(512) void attn_mfma(const uint16_t* __restrict__ qb,
                                                 const uint16_t* __restrict__ projb,
                                                 const uint16_t* __restrict__ ctxgb,
                                                 const float* __restrict__ kcumg,
                                                 uint16_t* __restrict__ attnb) {
  __shared__ uint16_t ctile[64][328];
  __shared__ uint16_t qs[128][72];
  __shared__ float kcums[MP_];
  __shared__ float dqs[128];
  __shared__ float denb[8][16];
  const int t = threadIdx.x, lane = t & 63, w = t >> 6;
  const int g = lane >> 4, r16 = lane & 15;
  const int nch = blockIdx.x, bh = blockIdx.y;
  const int b = bh >> 3, h = bh & 7;
  // stage ctx^T (bf16, slot order) and kcum (position order) once
  {
    int row = t >> 3, cb = t & 7;
#pragma unroll
    for (int cc = 0; cc < 5; ++cc) {
      int cN = cb * 40 + cc * 8;
      *(uint4*)&ctile[row][cN] = *(const uint4*)&ctxgb[((size_t)bh * 64 + row) * MP_ + cN];
    }
  }
  if (t < MP_) kcums[t] = kcumg[(size_t)bh * MP_ + t];

  for (int it = 0; it < 4; ++it) {
    const int nbase = nch * 512 + it * 128;
    __syncthreads();
    // stage q tile + dq
    {
      int row = t >> 2, c2 = t & 3;
      float sq = 0.f;
#pragma unroll
      for (int cc = 0; cc < 2; ++cc) {
        int c8 = c2 * 2 + cc;
        uint4 qv = *(const uint4*)&qb[((size_t)(b * N_ + nbase + row)) * DIM_ + h * DH_ + c8 * 8];
        *(uint4*)&qs[row][c8 * 8] = qv;
        float f[8]; unp8(qv, f);
        sq += f[0]*f[0]+f[1]*f[1]+f[2]*f[2]+f[3]*f[3]+f[4]*f[4]+f[5]*f[5]+f[6]*f[6]+f[7]*f[7];
      }
      sq += __shfl_xor(sq, 1); sq += __shfl_xor(sq, 2);
      if (c2 == 0) dqs[row] = 0.5f * CN_ * CN_ * sq;
    }
    __syncthreads();
    // S phase (swapped): C col = n (r16), row = m-local (4g+q); 18 m-tiles (288 positions)
    bf16x8 qf0 = *(const bf16x8*)&qs[w * 16 + r16][g * 8];
    bf16x8 qf1 = *(const bf16x8*)&qs[w * 16 + r16][32 + g * 8];
    f32x4 S[18];
#pragma unroll
    for (int mt = 0; mt < 18; ++mt) {
      bf16x8 pa0 = *(const bf16x8*)&projb[(mt * 16 + r16) * 64 + g * 8];
      bf16x8 pa1 = *(const bf16x8*)&projb[(mt * 16 + r16) * 64 + 32 + g * 8];
      f32x4 c4 = (f32x4){0.f, 0.f, 0.f, 0.f};
      c4 = __builtin_amdgcn_mfma_f32_16x16x32_bf16(pa0, qf0, c4, 0, 0, 0);
      S[mt] = __builtin_amdgcn_mfma_f32_16x16x32_bf16(pa1, qf1, c4, 0, 0, 0);
    }
    // row max over valid m (positions pi = 32*(mt>>1)+4*(mt&1)+8g+q)
    float rmax = -3.4e38f;
#pragma unroll
    for (int mt = 0; mt < 18; ++mt) {
#pragma unroll
      for (int q = 0; q < 4; ++q) {
        bool val = (mt < 16) || (256 + 4 * (mt & 1) + 8 * g + q < M_);
        if (val) rmax = fmaxf(rmax, CN_ * S[mt][q]);
      }
    }
    rmax = fmaxf(rmax, __shfl_xor(rmax, 16));
    rmax = fmaxf(rmax, __shfl_xor(rmax, 32));
    const float offv = rmax + dqs[w * 16 + r16];
    // exp + den partial + pack qp to bf16 (A-frag slot order via piperm/phinv)
    float denp = 0.f;
    uint32_t pk[18][2];
#pragma unroll
    for (int mt = 0; mt < 18; ++mt) {
      float4 kc4 = *(const float4*)&kcums[mt * 16 + 4 * g];
      float qp[4];
#pragma unroll
      for (int q = 0; q < 4; ++q) {
        bool val = (mt < 16) || (256 + 4 * (mt & 1) + 8 * g + q < M_);
        float e = RATIO_ * __expf(CN_ * S[mt][q] - offv) + REPS_;
        qp[q] = val ? e : 0.f;
        denp += qp[q] * f4get(kc4, q);
      }
      pk[mt][0] = pkbf(qp[0], qp[1]);
      pk[mt][1] = pkbf(qp[2], qp[3]);
    }
    denp += __shfl_xor(denp, 16);
    denp += __shfl_xor(denp, 32);
    if (lane < 16) denb[w][lane] = denp;
    // PV: A = qp (slot order), B = ctx^T[e] (slot order); 9 steps of 32 positions
    f32x4 o[4];
#pragma unroll
    for (int j = 0; j < 4; ++j) o[j] = (f32x4){0.f, 0.f, 0.f, 0.f};
#pragma unroll
    for (int s = 0; s < 9; ++s) {
      U8 af; af.u = make_uint4(pk[2 * s][0], pk[2 * s][1], pk[2 * s + 1][0], pk[2 * s + 1][1]);
#pragma unroll
      for (int j = 0; j < 4; ++j) {
        U8 cf; cf.u = *(const uint4*)&ctile[j * 16 + r16][s * 32 + g * 8];
        o[j] = __builtin_amdgcn_mfma_f32_16x16x32_bf16(af.v, cf.v, o[j], 0, 0, 0);
      }
    }
    float4 dv = *(const float4*)&denb[w][4 * g];
    float rd[4];
#pragma unroll
    for (int q = 0; q < 4; ++q) rd[q] = 1.0f / f4get(dv, q);
#pragma unroll
    for (int j = 0; j < 4; ++j) {
#pragma unroll
      for (int q = 0; q < 4; ++q) {
        float val = o[j][q] * rd[q];
        int n = nbase + w * 16 + 4 * g + q;
        attnb[((size_t)(b * N_ + n)) * DIM_ + h * DH_ + j * 16 + r16] = (uint16_t)f2bf(val);
      }
    }
  }
}

extern "C" void kernel_launch(void* const* d_in, const int* in_sizes, int n_in,
                              void* d_out, int out_size, void* d_ws, size_t ws_size,
                              hipStream_t stream) {
  const float* x = (const float*)d_in[0];
  const float* Wq = (const float*)d_in[1];
  const float* Wk = (const float*)d_in[2];
  const float* Wv = (const float*)d_in[3];
  const float* Wo = (const float*)d_in[4];
  const float* bo = (const float*)d_in[5];
  const float* proj = (const float*)d_in[6];
  float* out = (float*)d_out;

  char* ws = (char*)d_ws;
  size_t off = 0;
  auto alloc = [&](size_t bytes) {
    char* p = ws + off;
    off += (bytes + 255) & ~(size_t)255;
    return p;
  };
  // ws total ~49 MB
  uint16_t* wqT = (uint16_t*)alloc((size_t)512 * 512 * 2);
  uint16_t* wkT = (uint16_t*)alloc((size_t)512 * 512 * 2);
  uint16_t* wvT = (uint16_t*)alloc((size_t)512 * 512 * 2);
  uint16_t* woT = (uint16_t*)alloc((size_t)512 * 512 * 2);
  uint16_t* projb = (uint16_t*)alloc((size_t)MP_ * DH_ * 2);
  uint16_t* vTb = (uint16_t*)alloc((size_t)BNROWS_ * DIM_ * 2);   // vT, later attnb
  float* ctxp = (float*)alloc((size_t)NSPLIT_ * BH_ * 64 * MP_ * 4);
  float* kcump = (float*)alloc((size_t)NSPLIT_ * BH_ * MP_ * 4);
  uint16_t* ctxgb = (uint16_t*)alloc((size_t)BH_ * 64 * MP_ * 2);
  float* kcumg = (float*)alloc((size_t)BH_ * MP_ * 4);
  uint32_t* stab = (uint32_t*)alloc(256);
  // q,k staged in d_out (fully overwritten by the final GEMM afterwards)
  uint16_t* qb = (uint16_t*)d_out;
  uint16_t* kb = qb + (size_t)BNROWS_ * DIM_;
  uint16_t* attnb = vTb;

  init_stab<<<1, 1, 0, stream>>>(stab);
  cast_wt<<<1024, 256, 0, stream>>>(Wq, wqT);
  cast_wt<<<1024, 256, 0, stream>>>(Wk, wkT);
  cast_wt<<<1024, 256, 0, stream>>>(Wv, wvT);
  cast_wt<<<1024, 256, 0, stream>>>(Wo, woT);
  cast_projb<<<80, 256, 0, stream>>>(proj, projb);

  dim3 gg(256, 4);
  gemm_k<true, true, false><<<gg, 256, 0, stream>>>(x, wqT, qb, nullptr, 512, 512, 512);
  gemm_k<true, true, false><<<gg, 256, 0, stream>>>(x, wkT, kb, nullptr, 512, 512, 512);
  gemm_k<true, false, true><<<gg, 256, 0, stream>>>(x, wvT, vTb, nullptr, 512, 512, 512);

  stab_mfma<<<dim3(5, 64, 4), 256, 0, stream>>>(kb, projb, stab);
  ctx_mfma<<<dim3(5, 64, 2), 256, 0, stream>>>(kb, vTb, projb, stab, ctxp, kcump);
  merge_kernel<<<5120, 256, 0, stream>>>(ctxp, kcump, ctxgb, kcumg);
  attn_mfma<<<dim3(8, 64), 512, 0, stream>>>(qb, projb, ctxgb, kcumg, attnb);
  gemm_k<false, false, false><<<gg, 256, 0, stream>>>(attnb, woT, out, bo, 512, 512, 512);
}

// Round 5
// 303.115 us; speedup vs baseline: 6.3813x; 1.1669x over previous
//
#include <hip/hip_runtime.h>
#include <stdint.h>

// Problem constants
#define B_ 8
#define N_ 4096
#define H_ 8
#define DH_ 64
#define DIM_ 512
#define M_ 266
#define MP_ 320          // padded feature dim
#define BH_ 64
#define BNROWS_ 32768
#define CN_ 0.35355339059327373f      // 64^-0.25
#define RATIO_ 0.06131393394849658f   // 266^-0.5
#define EPS_ 1e-4f
#define REPS_ (RATIO_ * EPS_)

typedef __bf16 bf16x8 __attribute__((ext_vector_type(8)));
typedef float f32x4 __attribute__((ext_vector_type(4)));

union U8 { bf16x8 v; uint4 u; uint2 u2[2]; uint16_t s[8]; };

__device__ __forceinline__ uint32_t f2bf(float f) {
  uint32_t u = __float_as_uint(f);
  u += 0x7FFFu + ((u >> 16) & 1u);   // RNE
  return u >> 16;
}
__device__ __forceinline__ uint32_t pkbf(float a, float b) {
  uint32_t r;
  asm("v_cvt_pk_bf16_f32 %0, %1, %2" : "=v"(r) : "v"(a), "v"(b));
  return r;
}
__device__ __forceinline__ float bflo(uint32_t u) { return __uint_as_float(u << 16); }
__device__ __forceinline__ float bfhi(uint32_t u) { return __uint_as_float(u & 0xFFFF0000u); }
__device__ __forceinline__ void unp8(uint4 u, float* f) {
  f[0] = bflo(u.x); f[1] = bfhi(u.x); f[2] = bflo(u.y); f[3] = bfhi(u.y);
  f[4] = bflo(u.z); f[5] = bfhi(u.z); f[6] = bflo(u.w); f[7] = bfhi(u.w);
}
__device__ __forceinline__ float f4get(const float4& v, int i) {
  return ((const float*)&v)[i];
}
__device__ __forceinline__ uint32_t fenc(float f) {
  uint32_t u = __float_as_uint(f);
  return u ^ ((uint32_t)((int32_t)u >> 31) | 0x80000000u);
}
__device__ __forceinline__ float fdec(uint32_t e) {
  uint32_t u = (e & 0x80000000u) ? (e ^ 0x80000000u) : ~e;
  return __uint_as_float(u);
}
// position-permutation: proj row stored at position p holds original row pi(p)
__device__ __forceinline__ int piperm(int p) {
  int tmt = p >> 4, r = p & 15;
  return 32 * (tmt >> 1) + 8 * (r >> 2) + 4 * (tmt & 1) + (r & 3);
}
// inverse of attn A-frag slot->position map within a 32-window
__device__ __forceinline__ int phinv(int r) {
  int lo = r & 15;
  return 8 * (lo >> 2) + (lo & 3) + ((r >> 4) << 2);
}
// async global->LDS, 16B per lane; lds base must be wave-uniform
__device__ __forceinline__ void glds16(const uint16_t* g, uint16_t* l) {
  __builtin_amdgcn_global_load_lds(
      (const __attribute__((address_space(1))) void*)g,
      (__attribute__((address_space(3))) void*)l, 16, 0, 0);
}

__global__ void init_stab(uint32_t* s) { *s = fenc(-3.4e38f); }

// x fp32 -> bf16, layout-preserving
__global__ __launch_bounds__(256) void cast_x(const float* __restrict__ x,
                                              uint16_t* __restrict__ xb, int n4) {
  int i = blockIdx.x * 256 + threadIdx.x;
  if (i >= n4) return;
  float4 v = ((const float4*)x)[i];
  uint2 o;
  o.x = f2bf(v.x) | (f2bf(v.y) << 16);
  o.y = f2bf(v.z) | (f2bf(v.w) << 16);
  ((uint2*)xb)[i] = o;
}

// w: [512][512] (k,n) row-major -> wt: [512][512] (n,k) bf16
__global__ __launch_bounds__(256) void cast_wt(const float* __restrict__ w,
                                               uint16_t* __restrict__ wt) {
  int i = blockIdx.x * 256 + threadIdx.x;
  int k = i >> 9, n = i & 511;
  wt[(size_t)n * 512 + k] = (uint16_t)f2bf(w[i]);
}

// proj fp32 [266][64] -> projb bf16 [320][64], permuted rows, zero-padded
__global__ __launch_bounds__(256) void cast_projb(const float* __restrict__ proj,
                                                  uint16_t* __restrict__ projb) {
  int i = blockIdx.x * 256 + threadIdx.x;
  if (i >= MP_ * DH_) return;
  int p = i >> 6, d = i & 63;
  int pi = piperm(p);
  float v = (pi < M_) ? proj[pi * DH_ + d] : 0.f;
  projb[i] = (uint16_t)f2bf(v);
}

// ---------------- glds MFMA GEMM (A,B bf16, K=512) ----------------
// EPI 0: fp32 C + bias (Ndim 512). EPI 1: fused QKV (Ndim 1536; q/k bf16 rows, v transposed)
template <int EPI>
__global__ __launch_bounds__(256) void gemm_glds(const uint16_t* __restrict__ A,
                                                 const uint16_t* __restrict__ Bt,
                                                 float* __restrict__ outF,
                                                 const float* __restrict__ bias,
                                                 uint16_t* __restrict__ qb,
                                                 uint16_t* __restrict__ kbuf,
                                                 uint16_t* __restrict__ vTb) {
  __shared__ __align__(16) uint16_t As[2][128 * 32];
  __shared__ __align__(16) uint16_t Bs[2][128 * 32];
  const int t = threadIdx.x, lane = t & 63, w = t >> 6;
  const int g = lane >> 4, r16 = lane & 15;
  const int wr = (w >> 1) * 64, wc = (w & 1) * 64;
  const size_t rowA0 = (size_t)blockIdx.x * 128;
  const size_t rowB0 = (size_t)blockIdx.y * 128;
  const int K = 512;

  f32x4 acc[4][4];
#pragma unroll
  for (int i = 0; i < 4; ++i)
#pragma unroll
    for (int j = 0; j < 4; ++j) acc[i][j] = (f32x4){0.f, 0.f, 0.f, 0.f};

  auto stageG = [&](int kt, int buf) {
#pragma unroll
    for (int s = 0; s < 2; ++s) {
      const int row = w * 32 + s * 16;
      const uint16_t* ga = A + (rowA0 + row + (lane >> 2)) * (size_t)K + kt * 32 + (lane & 3) * 8;
      glds16(ga, &As[buf][row * 32]);
      const uint16_t* gb = Bt + (rowB0 + row + (lane >> 2)) * (size_t)K + kt * 32 + (lane & 3) * 8;
      glds16(gb, &Bs[buf][row * 32]);
    }
  };
  stageG(0, 0);
  for (int kt = 0; kt < 16; ++kt) {
    __syncthreads();    // drains glds (vmcnt) for buf kt&1
    if (kt + 1 < 16) stageG(kt + 1, (kt + 1) & 1);
    const uint16_t* as = As[kt & 1];
    const uint16_t* bs = Bs[kt & 1];
    bf16x8 af[4], bfr[4];
#pragma unroll
    for (int i = 0; i < 4; ++i)
      af[i] = *(const bf16x8*)&as[(wr + i * 16 + r16) * 32 + g * 8];
#pragma unroll
    for (int j = 0; j < 4; ++j)
      bfr[j] = *(const bf16x8*)&bs[(wc + j * 16 + r16) * 32 + g * 8];
#pragma unroll
    for (int i = 0; i < 4; ++i)
#pragma unroll
      for (int j = 0; j < 4; ++j)
        acc[i][j] = __builtin_amdgcn_mfma_f32_16x16x32_bf16(af[i], bfr[j], acc[i][j], 0, 0, 0);
  }
  // epilogue: C row = (lane>>4)*4+reg, col = lane&15
  const int region = blockIdx.y >> 2;              // EPI1: 0=q 1=k 2=v
  const int lcolBase = (blockIdx.y & 3) * 128;
#pragma unroll
  for (int i = 0; i < 4; ++i) {
    const size_t row0 = rowA0 + wr + i * 16 + g * 4;
#pragma unroll
    for (int j = 0; j < 4; ++j) {
      if constexpr (EPI == 0) {
        const size_t col = rowB0 + wc + j * 16 + r16;
        float badd = bias ? bias[col] : 0.f;
#pragma unroll
        for (int q = 0; q < 4; ++q)
          outF[(row0 + q) * (size_t)512 + col] = acc[i][j][q] + badd;
      } else {
        const int lcol = lcolBase + wc + j * 16 + r16;
        if (region == 2) {
          int bb = (int)(row0 >> 12), n = (int)(row0 & 4095);
          int hh = lcol >> 6, e = lcol & 63;
          uint2 o;
          o.x = pkbf(acc[i][j][0], acc[i][j][1]);
          o.y = pkbf(acc[i][j][2], acc[i][j][3]);
          *(uint2*)&vTb[((size_t)((bb * 8 + hh) * 64 + e)) * 4096 + n] = o;
        } else {
          uint16_t* dst = region ? kbuf : qb;
#pragma unroll
          for (int q = 0; q < 4; ++q)
            dst[(row0 + q) * (size_t)512 + lcol] = (uint16_t)f2bf(acc[i][j][q]);
        }
      }
    }
  }
}

// ---------------- AF32 MFMA GEMM (fallback path, proven) ----------------
#define GKP_ 40
template <bool AF32, bool CBF16, bool VT>
__global__ __launch_bounds__(256) void gemm_k(const void* __restrict__ Av,
                                              const uint16_t* __restrict__ Bt,
                                              void* __restrict__ Cv,
                                              const float* __restrict__ bias,
                                              int Ndim, int Kdim, int lda) {
  __shared__ uint16_t As[2][128 * GKP_];
  __shared__ uint16_t Bs[2][128 * GKP_];
  const int t = threadIdx.x;
  const int lane = t & 63;
  const int wave = t >> 6;
  const int wr = (wave >> 1) * 64, wc = (wave & 1) * 64;
  const int g = lane >> 4, r16 = lane & 15;
  const int srow = t >> 2;
  const int skk = (t & 3) * 8;
  const size_t rowA0 = (size_t)blockIdx.x * 128;
  const size_t rowB0 = (size_t)blockIdx.y * 128;

  f32x4 acc[4][4];
#pragma unroll
  for (int i = 0; i < 4; ++i)
#pragma unroll
    for (int j = 0; j < 4; ++j) acc[i][j] = (f32x4){0.f, 0.f, 0.f, 0.f};

  const int NK = Kdim >> 5;
  auto stage = [&](int kt, int buf) {
    uint4 a0, a1;
    if constexpr (AF32) {
      const float* ga = (const float*)Av + (rowA0 + srow) * (size_t)lda + kt * 32 + skk;
      float4 x0 = *(const float4*)ga;
      float4 x1 = *(const float4*)(ga + 4);
      float4 y0 = *(const float4*)(ga + 64 * (size_t)lda);
      float4 y1 = *(const float4*)(ga + 64 * (size_t)lda + 4);
      a0.x = f2bf(x0.x) | (f2bf(x0.y) << 16);
      a0.y = f2bf(x0.z) | (f2bf(x0.w) << 16);
      a0.z = f2bf(x1.x) | (f2bf(x1.y) << 16);
      a0.w = f2bf(x1.z) | (f2bf(x1.w) << 16);
      a1.x = f2bf(y0.x) | (f2bf(y0.y) << 16);
      a1.y = f2bf(y0.z) | (f2bf(y0.w) << 16);
      a1.z = f2bf(y1.x) | (f2bf(y1.y) << 16);
      a1.w = f2bf(y1.z) | (f2bf(y1.w) << 16);
    } else {
      const uint16_t* ga = (const uint16_t*)Av + (rowA0 + srow) * (size_t)lda + kt * 32 + skk;
      a0 = *(const uint4*)ga;
      a1 = *(const uint4*)(ga + 64 * (size_t)lda);
    }
    const uint16_t* gb = Bt + (rowB0 + srow) * (size_t)Kdim + kt * 32 + skk;
    uint4 b0 = *(const uint4*)gb;
    uint4 b1 = *(const uint4*)(gb + 64 * (size_t)Kdim);
    *(uint4*)&As[buf][srow * GKP_ + skk] = a0;
    *(uint4*)&As[buf][(srow + 64) * GKP_ + skk] = a1;
    *(uint4*)&Bs[buf][srow * GKP_ + skk] = b0;
    *(uint4*)&Bs[buf][(srow + 64) * GKP_ + skk] = b1;
  };
  stage(0, 0);
  for (int kt = 0; kt < NK; ++kt) {
    __syncthreads();
    if (kt + 1 < NK) stage(kt + 1, (kt + 1) & 1);
    const uint16_t* as = As[kt & 1];
    const uint16_t* bs = Bs[kt & 1];
    bf16x8 af[4], bfr[4];
#pragma unroll
    for (int i = 0; i < 4; ++i)
      af[i] = *(const bf16x8*)&as[(wr + i * 16 + r16) * GKP_ + g * 8];
#pragma unroll
    for (int j = 0; j < 4; ++j)
      bfr[j] = *(const bf16x8*)&bs[(wc + j * 16 + r16) * GKP_ + g * 8];
#pragma unroll
    for (int i = 0; i < 4; ++i)
#pragma unroll
      for (int j = 0; j < 4; ++j)
        acc[i][j] = __builtin_amdgcn_mfma_f32_16x16x32_bf16(af[i], bfr[j], acc[i][j], 0, 0, 0);
  }
#pragma unroll
  for (int i = 0; i < 4; ++i) {
    const size_t row0 = rowA0 + wr + i * 16 + g * 4;
#pragma unroll
    for (int j = 0; j < 4; ++j) {
      const size_t col = rowB0 + wc + j * 16 + r16;
      if constexpr (VT) {
        int bb = (int)(row0 >> 12), n = (int)(row0 & 4095);
        int hh = (int)(col >> 6), e = (int)(col & 63);
        uint2 o;
        o.x = pkbf(acc[i][j][0], acc[i][j][1]);
        o.y = pkbf(acc[i][j][2], acc[i][j][3]);
        *(uint2*)&((uint16_t*)Cv)[((size_t)((bb * 8 + hh) * 64 + e)) * 4096 + n] = o;
      } else {
        float badd = bias ? bias[col] : 0.f;
#pragma unroll
        for (int q = 0; q < 4; ++q) {
          float val = acc[i][j][q] + badd;
          if constexpr (CBF16)
            ((uint16_t*)Cv)[(row0 + q) * (size_t)Ndim + col] = (uint16_t)f2bf(val);
          else
            ((float*)Cv)[(row0 + q) * (size_t)Ndim + col] = val;
        }
      }
    }
  }
}

// ---------------- stab: global max of CN*(k . proj), all 5 m-tiles per staged k ----------------
// grid (bh=64, ns=16), 256 thr (4 waves)
__global__ __launch_bounds__(256) void stab2_mfma(const uint16_t* __restrict__ kb,
                                                  const uint16_t* __restrict__ projb,
                                                  uint32_t* __restrict__ stab) {
  __shared__ uint16_t kt[2][32][72];
  __shared__ float wred[4];
  const int t = threadIdx.x, lane = t & 63, w = t >> 6;
  const int g = lane >> 4, r16 = lane & 15;
  const int bh = blockIdx.x, ns = blockIdx.y;
  const int b = bh >> 3, h = bh & 7;
  bf16x8 pj[5][2];
  bool mval[5];
#pragma unroll
  for (int mt = 0; mt < 5; ++mt) {
    int m16 = mt * 64 + w * 16;
    pj[mt][0] = *(const bf16x8*)&projb[(m16 + r16) * 64 + g * 8];
    pj[mt][1] = *(const bf16x8*)&projb[(m16 + r16) * 64 + 32 + g * 8];
    mval[mt] = piperm(m16 + r16) < M_;
  }
  auto stage = [&](int it, int buf) {
    int n0 = ns * 256 + it * 32;
    int row = t >> 3, c8 = t & 7;
    *(uint4*)&kt[buf][row][c8 * 8] =
        *(const uint4*)&kb[((size_t)(b * N_ + n0 + row)) * DIM_ + h * DH_ + c8 * 8];
  };
  stage(0, 0);
  __syncthreads();
  float vmax = -3.4e38f;
  for (int it = 0; it < 8; ++it) {
    int cur = it & 1;
    if (it + 1 < 8) stage(it + 1, cur ^ 1);
    bf16x8 ka[2][2];
#pragma unroll
    for (int nsub = 0; nsub < 2; ++nsub) {
      ka[nsub][0] = *(const bf16x8*)&kt[cur][nsub * 16 + r16][g * 8];
      ka[nsub][1] = *(const bf16x8*)&kt[cur][nsub * 16 + r16][32 + g * 8];
    }
#pragma unroll
    for (int mt = 0; mt < 5; ++mt) {
#pragma unroll
      for (int nsub = 0; nsub < 2; ++nsub) {
        f32x4 c4 = (f32x4){0.f, 0.f, 0.f, 0.f};
        c4 = __builtin_amdgcn_mfma_f32_16x16x32_bf16(ka[nsub][0], pj[mt][0], c4, 0, 0, 0);
        c4 = __builtin_amdgcn_mfma_f32_16x16x32_bf16(ka[nsub][1], pj[mt][1], c4, 0, 0, 0);
        if (mval[mt])
          vmax = fmaxf(vmax, fmaxf(fmaxf(c4[0], c4[1]), fmaxf(c4[2], c4[3])));
      }
    }
    __syncthreads();
  }
#pragma unroll
  for (int off = 32; off; off >>= 1) vmax = fmaxf(vmax, __shfl_xor(vmax, off));
  if (lane == 0) wred[w] = vmax;
  __syncthreads();
  if (t == 0) {
    float m = fmaxf(fmaxf(wred[0], wred[1]), fmaxf(wred[2], wred[3]));
    atomicMax(stab, fenc(CN_ * m));
  }
}

// ---------------- ctx: kp-feature + kp^T @ v, MFMA ----------------
// grid (mt=5, bh=64, ns=NS), 256 thr (4 waves); iters = 4096/(32*NS)
__global__ __launch_bounds__(256) void ctx_mfma(const uint16_t* __restrict__ kb,
                                                const uint16_t* __restrict__ vTb,
                                                const uint16_t* __restrict__ projb,
                                                const uint32_t* __restrict__ stab_e,
                                                float* __restrict__ ctxp,
                                                float* __restrict__ kcump,
                                                int iters) {
  __shared__ uint16_t kt[2][32][72];
  __shared__ uint16_t vt[2][64][40];
  __shared__ float dk2[2][32];
  __shared__ uint16_t kpb[4][16][40];
  const int t = threadIdx.x, lane = t & 63, w = t >> 6;
  const int g = lane >> 4, r16 = lane & 15;
  const int mt = blockIdx.x, bh = blockIdx.y, ns = blockIdx.z;
  const int b = bh >> 3, h = bh & 7;
  const int m16 = mt * 64 + w * 16;
  const float stab = fdec(*stab_e);
  const bool mvalid = piperm(m16 + r16) < M_;
  bf16x8 pj0 = *(const bf16x8*)&projb[(m16 + r16) * 64 + g * 8];
  bf16x8 pj1 = *(const bf16x8*)&projb[(m16 + r16) * 64 + 32 + g * 8];

  auto stage = [&](int it, int buf) {
    int n0 = (ns * iters + it) * 32;
    {
      int row = t >> 3, c8 = t & 7;
      uint4 kv = *(const uint4*)&kb[((size_t)(b * N_ + n0 + row)) * DIM_ + h * DH_ + c8 * 8];
      *(uint4*)&kt[buf][row][c8 * 8] = kv;
      float f[8]; unp8(kv, f);
      float sq = f[0]*f[0]+f[1]*f[1]+f[2]*f[2]+f[3]*f[3]+f[4]*f[4]+f[5]*f[5]+f[6]*f[6]+f[7]*f[7];
      sq += __shfl_xor(sq, 1); sq += __shfl_xor(sq, 2); sq += __shfl_xor(sq, 4);
      if (c8 == 0) dk2[buf][row] = 0.5f * CN_ * CN_ * sq;
    }
    {
      int e = t >> 2, c = t & 3;
      uint4 vv = *(const uint4*)&vTb[((size_t)(bh * 64 + e)) * 4096 + n0 + c * 8];
      *(uint4*)&vt[buf][e][c * 8] = vv;
    }
  };
  f32x4 acc[4];
#pragma unroll
  for (int j = 0; j < 4; ++j) acc[j] = (f32x4){0.f, 0.f, 0.f, 0.f};
  float kcacc = 0.f;

  stage(0, 0);
  __syncthreads();
  for (int it = 0; it < iters; ++it) {
    int cur = it & 1;
    if (it + 1 < iters) stage(it + 1, cur ^ 1);
#pragma unroll
    for (int nsub = 0; nsub < 2; ++nsub) {
      bf16x8 ka0 = *(const bf16x8*)&kt[cur][nsub * 16 + r16][g * 8];
      bf16x8 ka1 = *(const bf16x8*)&kt[cur][nsub * 16 + r16][32 + g * 8];
      f32x4 c4 = (f32x4){0.f, 0.f, 0.f, 0.f};
      c4 = __builtin_amdgcn_mfma_f32_16x16x32_bf16(ka0, pj0, c4, 0, 0, 0);
      c4 = __builtin_amdgcn_mfma_f32_16x16x32_bf16(ka1, pj1, c4, 0, 0, 0);
      float4 dkv = *(const float4*)&dk2[cur][nsub * 16 + 4 * g];
      float kp[4];
#pragma unroll
      for (int q = 0; q < 4; ++q) {
        float arg = CN_ * c4[q] - f4get(dkv, q) - stab;
        float e = RATIO_ * __expf(arg) + REPS_;
        kp[q] = mvalid ? e : 0.f;
        kcacc += kp[q];
      }
      *(uint2*)&kpb[w][r16][nsub * 16 + 4 * g] = make_uint2(pkbf(kp[0], kp[1]), pkbf(kp[2], kp[3]));
    }
    U8 kq; kq.u = *(const uint4*)&kpb[w][r16][g * 8];
#pragma unroll
    for (int j = 0; j < 4; ++j) {
      U8 vf; vf.u = *(const uint4*)&vt[cur][j * 16 + r16][g * 8];
      acc[j] = __builtin_amdgcn_mfma_f32_16x16x32_bf16(kq.v, vf.v, acc[j], 0, 0, 0);
    }
    __syncthreads();
  }
#pragma unroll
  for (int j = 0; j < 4; ++j) {
    float4 o = make_float4(acc[j][0], acc[j][1], acc[j][2], acc[j][3]);
    *(float4*)&ctxp[(((size_t)ns * BH_ + bh) * 64 + j * 16 + r16) * MP_ + m16 + 4 * g] = o;
  }
  kcacc += __shfl_xor(kcacc, 16);
  kcacc += __shfl_xor(kcacc, 32);
  if (lane < 16) kcump[((size_t)ns * BH_ + bh) * MP_ + m16 + lane] = kcacc;
}

// merge partials: ctx -> bf16 [bh][e][320] in SLOT order (phinv), kcum -> fp32 [bh][320]
__global__ __launch_bounds__(256) void merge_kernel(const float* __restrict__ ctxp,
                                                    const float* __restrict__ kcump,
                                                    uint16_t* __restrict__ ctxgb,
                                                    float* __restrict__ kcumg,
                                                    int nsp) {
  int idx = blockIdx.x * 256 + threadIdx.x;
  const int total = BH_ * 64 * MP_;
  if (idx < total) {
    float s = 0.f;
    for (int p = 0; p < nsp; ++p) s += ctxp[(size_t)p * total + idx];
    int row = idx / MP_;
    int pos = idx - row * MP_;
    int col = (pos & ~31) + phinv(pos & 31);
    ctxgb[(size_t)row * MP_ + col] = (uint16_t)f2bf(s);
  }
  const int ktotal = BH_ * MP_;
  if (idx < ktotal) {
    float s = 0.f;
    for (int p = 0; p < nsp; ++p) s += kcump[(size_t)p * ktotal + idx];
    kcumg[idx] = s;
  }
}

// ---------------- attention output: qp feature + qp @ ctx, MFMA ----------------
// grid (nchunk=8, bh=64), 512 thr (8 waves)
__global__ __launch_bounds__(512) void attn_mfma(const uint16_t* __restrict__ qb,
                                                 const uint16_t* __restrict__ projb,
                                                 const uint16_t* __restrict__ ctxgb,
                                                 const float* __restrict__ kcumg,
                                                 uint16_t* __restrict__ attnb) {
  __shared__ uint16_t ctile[64][328];
  __shared__ uint16_t qs[128][72];
  __shared__ float kcums[MP_];
  __shared__ float dqs[128];
  __shared__ float denb[8][16];
  const int t = threadIdx.x, lane = t & 63, w = t >> 6;
  const int g = lane >> 4, r16 = lane & 15;
  const int nch = blockIdx.x, bh = blockIdx.y;
  const int b = bh >> 3, h = bh & 7;
  {
    int row = t >> 3, cb = t & 7;
#pragma unroll
    for (int cc = 0; cc < 5; ++cc) {
      int cN = cb * 40 + cc * 8;
      *(uint4*)&ctile[row][cN] = *(const uint4*)&ctxgb[((size_t)bh * 64 + row) * MP_ + cN];
    }
  }
  if (t < MP_) kcums[t] = kcumg[(size_t)bh * MP_ + t];

  for (int it = 0; it < 4; ++it) {
    const int nbase = nch * 512 + it * 128;
    __syncthreads();
    {
      int row = t >> 2, c2 = t & 3;
      float sq = 0.f;
#pragma unroll
      for (int cc = 0; cc < 2; ++cc) {
        int c8 = c2 * 2 + cc;
        uint4 qv = *(const uint4*)&qb[((size_t)(b * N_ + nbase + row)) * DIM_ + h * DH_ + c8 * 8];
        *(uint4*)&qs[row][c8 * 8] = qv;
        float f[8]; unp8(qv, f);
        sq += f[0]*f[0]+f[1]*f[1]+f[2]*f[2]+f[3]*f[3]+f[4]*f[4]+f[5]*f[5]+f[6]*f[6]+f[7]*f[7];
      }
      sq += __shfl_xor(sq, 1); sq += __shfl_xor(sq, 2);
      if (c2 == 0) dqs[row] = 0.5f * CN_ * CN_ * sq;
    }
    __syncthreads();
    bf16x8 qf0 = *(const bf16x8*)&qs[w * 16 + r16][g * 8];
    bf16x8 qf1 = *(const bf16x8*)&qs[w * 16 + r16][32 + g * 8];
    f32x4 S[18];
#pragma unroll
    for (int mt = 0; mt < 18; ++mt) {
      bf16x8 pa0 = *(const bf16x8*)&projb[(mt * 16 + r16) * 64 + g * 8];
      bf16x8 pa1 = *(const bf16x8*)&projb[(mt * 16 + r16) * 64 + 32 + g * 8];
      f32x4 c4 = (f32x4){0.f, 0.f, 0.f, 0.f};
      c4 = __builtin_amdgcn_mfma_f32_16x16x32_bf16(pa0, qf0, c4, 0, 0, 0);
      S[mt] = __builtin_amdgcn_mfma_f32_16x16x32_bf16(pa1, qf1, c4, 0, 0, 0);
    }
    float rmax = -3.4e38f;
#pragma unroll
    for (int mt = 0; mt < 18; ++mt) {
#pragma unroll
      for (int q = 0; q < 4; ++q) {
        bool val = (mt < 16) || (256 + 4 * (mt & 1) + 8 * g + q < M_);
        if (val) rmax = fmaxf(rmax, CN_ * S[mt][q]);
      }
    }
    rmax = fmaxf(rmax, __shfl_xor(rmax, 16));
    rmax = fmaxf(rmax, __shfl_xor(rmax, 32));
    const float offv = rmax + dqs[w * 16 + r16];
    float denp = 0.f;
    uint32_t pk[18][2];
#pragma unroll
    for (int mt = 0; mt < 18; ++mt) {
      float4 kc4 = *(const float4*)&kcums[mt * 16 + 4 * g];
      float qp[4];
#pragma unroll
      for (int q = 0; q < 4; ++q) {
        bool val = (mt < 16) || (256 + 4 * (mt & 1) + 8 * g + q < M_);
        float e = RATIO_ * __expf(CN_ * S[mt][q] - offv) + REPS_;
        qp[q] = val ? e : 0.f;
        denp += qp[q] * f4get(kc4, q);
      }
      pk[mt][0] = pkbf(qp[0], qp[1]);
      pk[mt][1] = pkbf(qp[2], qp[3]);
    }
    denp += __shfl_xor(denp, 16);
    denp += __shfl_xor(denp, 32);
    if (lane < 16) denb[w][lane] = denp;
    f32x4 o[4];
#pragma unroll
    for (int j = 0; j < 4; ++j) o[j] = (f32x4){0.f, 0.f, 0.f, 0.f};
#pragma unroll
    for (int s = 0; s < 9; ++s) {
      U8 af; af.u = make_uint4(pk[2 * s][0], pk[2 * s][1], pk[2 * s + 1][0], pk[2 * s + 1][1]);
#pragma unroll
      for (int j = 0; j < 4; ++j) {
        U8 cf; cf.u = *(const uint4*)&ctile[j * 16 + r16][s * 32 + g * 8];
        o[j] = __builtin_amdgcn_mfma_f32_16x16x32_bf16(af.v, cf.v, o[j], 0, 0, 0);
      }
    }
    float4 dv = *(const float4*)&denb[w][4 * g];
    float rd[4];
#pragma unroll
    for (int q = 0; q < 4; ++q) rd[q] = 1.0f / f4get(dv, q);
#pragma unroll
    for (int j = 0; j < 4; ++j) {
#pragma unroll
      for (int q = 0; q < 4; ++q) {
        float val = o[j][q] * rd[q];
        int n = nbase + w * 16 + 4 * g + q;
        attnb[((size_t)(b * N_ + n)) * DIM_ + h * DH_ + j * 16 + r16] = (uint16_t)f2bf(val);
      }
    }
  }
}

extern "C" void kernel_launch(void* const* d_in, const int* in_sizes, int n_in,
                              void* d_out, int out_size, void* d_ws, size_t ws_size,
                              hipStream_t stream) {
  const float* x = (const float*)d_in[0];
  const float* Wq = (const float*)d_in[1];
  const float* Wk = (const float*)d_in[2];
  const float* Wv = (const float*)d_in[3];
  const float* Wo = (const float*)d_in[4];
  const float* bo = (const float*)d_in[5];
  const float* proj = (const float*)d_in[6];
  float* out = (float*)d_out;

  // tier selection on ws_size (constant across calls -> deterministic)
  const bool tierA = ws_size >= (size_t)95000000;                 // xb + NS=4 (~93.3MB)
  const int NS = (tierA || ws_size >= (size_t)61000000) ? 4 : 2;  // tierB ~59.7MB, tierC ~49.0MB

  char* ws = (char*)d_ws;
  size_t off = 0;
  auto alloc = [&](size_t bytes) {
    char* p = ws + off;
    off += (bytes + 255) & ~(size_t)255;
    return p;
  };
  uint16_t* wqkvT = (uint16_t*)alloc((size_t)1536 * 512 * 2);   // rows: q cols, k cols, v cols
  uint16_t* woT = (uint16_t*)alloc((size_t)512 * 512 * 2);
  uint16_t* projb = (uint16_t*)alloc((size_t)MP_ * DH_ * 2);
  uint16_t* vTb = (uint16_t*)alloc((size_t)BNROWS_ * DIM_ * 2);  // vT, later attnb
  float* ctxp = (float*)alloc((size_t)NS * BH_ * 64 * MP_ * 4);
  float* kcump = (float*)alloc((size_t)NS * BH_ * MP_ * 4);
  uint16_t* ctxgb = (uint16_t*)alloc((size_t)BH_ * 64 * MP_ * 2);
  float* kcumg = (float*)alloc((size_t)BH_ * MP_ * 4);
  uint32_t* stab = (uint32_t*)alloc(256);
  uint16_t* xb = tierA ? (uint16_t*)alloc((size_t)BNROWS_ * DIM_ * 2) : nullptr;
  // q,k staged in d_out (fully overwritten by the final GEMM afterwards)
  uint16_t* qb = (uint16_t*)d_out;
  uint16_t* kb = qb + (size_t)BNROWS_ * DIM_;
  uint16_t* attnb = vTb;

  init_stab<<<1, 1, 0, stream>>>(stab);
  cast_wt<<<1024, 256, 0, stream>>>(Wq, wqkvT);
  cast_wt<<<1024, 256, 0, stream>>>(Wk, wqkvT + (size_t)512 * 512);
  cast_wt<<<1024, 256, 0, stream>>>(Wv, wqkvT + (size_t)1024 * 512);
  cast_wt<<<1024, 256, 0, stream>>>(Wo, woT);
  cast_projb<<<80, 256, 0, stream>>>(proj, projb);

  if (tierA) {
    cast_x<<<16384, 256, 0, stream>>>(x, xb, BNROWS_ * DIM_ / 4);
    gemm_glds<1><<<dim3(256, 12), 256, 0, stream>>>(xb, wqkvT, nullptr, nullptr, qb, kb, vTb);
  } else {
    dim3 gg(256, 4);
    gemm_k<true, true, false><<<gg, 256, 0, stream>>>(x, wqkvT, qb, nullptr, 512, 512, 512);
    gemm_k<true, true, false><<<gg, 256, 0, stream>>>(x, wqkvT + (size_t)512 * 512, kb, nullptr, 512, 512, 512);
    gemm_k<true, false, true><<<gg, 256, 0, stream>>>(x, wqkvT + (size_t)1024 * 512, vTb, nullptr, 512, 512, 512);
  }

  stab2_mfma<<<dim3(64, 16), 256, 0, stream>>>(kb, projb, stab);
  ctx_mfma<<<dim3(5, 64, NS), 256, 0, stream>>>(kb, vTb, projb, stab, ctxp, kcump, 128 / NS);
  merge_kernel<<<5120, 256, 0, stream>>>(ctxp, kcump, ctxgb, kcumg, NS);
  attn_mfma<<<dim3(8, 64), 512, 0, stream>>>(qb, projb, ctxgb, kcumg, attnb);
  gemm_k<false, false, false><<<dim3(256, 4), 256, 0, stream>>>(attnb, woT, out, bo, 512, 512, 512);
}